// Round 9
// baseline (237.491 us; speedup 1.0000x reference)
//
#include <hip/hip_runtime.h>

// MHA: B=2, S=2048, D=1024, H=16, DK=64. All GEMMs are x @ W.T (+bias).
// R9 (attn): R8 core kept (32x32 MFMA, swap23-permuted K staging, register-
// resident P, 1 barrier/iter). Changes:
//  - 2-wave / 64-q blocks, grid 1024 -> 4 blocks/CU, 4 barrier domains.
//  - XCD-aware bh clustering: all 32 q-blocks of one (b,h) on one XCD ->
//    K/V (2 MB/XCD) stays in that XCD's L2. Expect FETCH 71 -> ~30 MB.
//  - prefetch pointers loop-carried (+constant), uniform last-iter skip.

#define S_LEN 2048
#define BATCH 2
#define DM    1024
#define NH    16
#define DKH   64
#define BS    (BATCH * S_LEN)   // 4096 rows

typedef _Float16 f16x8 __attribute__((ext_vector_type(8)));
typedef _Float16 f16x4 __attribute__((ext_vector_type(4)));
typedef _Float16 f16x2 __attribute__((ext_vector_type(2)));
typedef __fp16   h16x2 __attribute__((ext_vector_type(2)));
typedef float    f32x4 __attribute__((ext_vector_type(4)));
typedef float    f32x16 __attribute__((ext_vector_type(16)));

__device__ __forceinline__ f16x2 pk_f16(float a, float b) {
  h16x2 r = __builtin_amdgcn_cvt_pkrtz(a, b);
  return __builtin_bit_cast(f16x2, r);
}

__device__ __forceinline__ void gld16(const void* g, void* l) {
  __builtin_amdgcn_global_load_lds(
      (const __attribute__((address_space(1))) void*)g,
      (__attribute__((address_space(3))) void*)l, 16, 0, 0);
}

__device__ __forceinline__ float fast_exp2(float x) {
#if __has_builtin(__builtin_amdgcn_exp2f)
  return __builtin_amdgcn_exp2f(x);
#else
  return exp2f(x);
#endif
}

__device__ __forceinline__ int swap23(int x) {   // swap bits 2 and 3 (involution)
  return (x & ~12) | ((x & 4) << 1) | ((x & 8) >> 1);
}

// ---------------- fp32 -> fp16 conversion ----------------
__global__ __launch_bounds__(256) void cvt_all(
    const float* __restrict__ q, const float* __restrict__ k, const float* __restrict__ v,
    const float* __restrict__ wq, const float* __restrict__ wk,
    const float* __restrict__ wv, const float* __restrict__ wo,
    _Float16* __restrict__ xq, _Float16* __restrict__ xk, _Float16* __restrict__ xv,
    _Float16* __restrict__ w16)
{
  const int y = blockIdx.y;
  const float* src; _Float16* dst; int n;
  if (y == 0)      { src = q;  dst = xq; n = BS * DM; }
  else if (y == 1) { src = k;  dst = xk; n = BS * DM; }
  else if (y == 2) { src = v;  dst = xv; n = BS * DM; }
  else {
    src = (y == 3) ? wq : ((y == 4) ? wk : ((y == 5) ? wv : wo));
    dst = w16 + (size_t)(y - 3) * (DM * DM);
    n = DM * DM;
  }
  int i0 = (blockIdx.x * 256 + threadIdx.x) * 4;
  if (i0 < n) {
    float4 f = *(const float4*)(src + i0);
    f16x2 lo = pk_f16(f.x, f.y);
    f16x2 hi = pk_f16(f.z, f.w);
    f16x4 hh; hh[0] = lo[0]; hh[1] = lo[1]; hh[2] = hi[0]; hh[3] = hi[1];
    *(f16x4*)(dst + i0) = hh;
  }
}

// ---------------- 128x128-tile GEMM: C = (A @ W^T + bias)*oscale ----------------
template <typename OUT_T, bool VT>
__device__ __forceinline__ void gemm_core(
    const _Float16* __restrict__ A, const _Float16* __restrict__ W,
    const float* __restrict__ bias, OUT_T* __restrict__ out, float oscale)
{
  const int tid  = threadIdx.x;
  const int l    = tid & 63;
  const int wv   = tid >> 6;
  const int c    = l & 15, quad = l >> 4;
  const int m0   = blockIdx.y * 128, n0 = blockIdx.x * 128;
  const int wm   = wv & 1, wn = wv >> 1;
  __shared__ _Float16 sA[128 * 64];
  __shared__ _Float16 sB[128 * 64];

  const _Float16* gA[4]; const _Float16* gB[4];
#pragma unroll
  for (int p = 0; p < 4; ++p) {
    int s = tid + p * 256, r = s >> 3, g = (s & 7) ^ (r & 7);
    gA[p] = A + (size_t)(m0 + r) * DM + g * 8;
    gB[p] = W + (size_t)(n0 + r) * DM + g * 8;
  }
  const int cx = c & 7;

  f32x4 acc[4][4] = {};
  for (int k0 = 0; k0 < DM; k0 += 64) {
    __syncthreads();
#pragma unroll
    for (int p = 0; p < 4; ++p) {
      gld16(gA[p] + k0, sA + (tid + p * 256) * 8);
      gld16(gB[p] + k0, sB + (tid + p * 256) * 8);
    }
    __syncthreads();
#pragma unroll
    for (int ks = 0; ks < 2; ++ks) {
      f16x8 af[4], bf[4];
#pragma unroll
      for (int i = 0; i < 4; ++i)
        af[i] = *(const f16x8*)&sA[(wm * 64 + i * 16 + c) * 64 + ((ks * 4 + quad) ^ cx) * 8];
#pragma unroll
      for (int j = 0; j < 4; ++j)
        bf[j] = *(const f16x8*)&sB[(wn * 64 + j * 16 + c) * 64 + ((ks * 4 + quad) ^ cx) * 8];
#pragma unroll
      for (int i = 0; i < 4; ++i)
#pragma unroll
        for (int j = 0; j < 4; ++j)
          acc[i][j] = __builtin_amdgcn_mfma_f32_16x16x32_f16(af[i], bf[j], acc[i][j], 0, 0, 0);
    }
  }
  if constexpr (VT) {
#pragma unroll
    for (int j = 0; j < 4; ++j) {
      int col = n0 + wn * 64 + j * 16 + c;
      float bb = bias[col];
      int hh = col >> 6, dd = col & 63;
#pragma unroll
      for (int i = 0; i < 4; ++i) {
        int row = m0 + wm * 64 + i * 16 + quad * 4;
        int bb2 = row >> 11, ss = row & (S_LEN - 1);
        _Float16* dst = (_Float16*)out + ((size_t)(bb2 * NH + hh) * DKH + dd) * S_LEN + ss;
        f16x4 v4;
#pragma unroll
        for (int r = 0; r < 4; ++r) v4[r] = (_Float16)((acc[i][j][r] + bb) * oscale);
        *(f16x4*)dst = v4;
      }
    }
  } else {
#pragma unroll
    for (int j = 0; j < 4; ++j) {
      int col = n0 + wn * 64 + j * 16 + c;
      float bb = bias[col];
#pragma unroll
      for (int i = 0; i < 4; ++i) {
        int row = m0 + wm * 64 + i * 16 + quad * 4;
#pragma unroll
        for (int r = 0; r < 4; ++r) {
          float vv = (acc[i][j][r] + bb) * oscale;
          out[(size_t)(row + r) * DM + col] = (OUT_T)vv;
        }
      }
    }
  }
}

#define SC_Q (0.125f * 1.44269504088896340736f)   // 1/sqrt(64) * log2(e)

__global__ __launch_bounds__(256) void proj3(
    const _Float16* __restrict__ xq, const _Float16* __restrict__ xk,
    const _Float16* __restrict__ xv, const _Float16* __restrict__ w16,
    const float* __restrict__ bq, const float* __restrict__ bk, const float* __restrict__ bv,
    _Float16* __restrict__ Q, _Float16* __restrict__ K, _Float16* __restrict__ Vt)
{
  const int z = blockIdx.z;
  if (z == 2) {
    gemm_core<_Float16, true>(xv, w16 + (size_t)2 * DM * DM, bv, Vt, 1.0f);
  } else if (z == 0) {
    gemm_core<_Float16, false>(xq, w16, bq, Q, SC_Q);
  } else {
    gemm_core<_Float16, false>(xk, w16 + (size_t)DM * DM, bk, K, 1.0f);
  }
}

__global__ __launch_bounds__(256) void out_gemm(
    const _Float16* __restrict__ ctx, const _Float16* __restrict__ wo,
    const float* __restrict__ bo, float* __restrict__ out)
{
  gemm_core<float, false>(ctx, wo, bo, out, 1.0f);
}

// ---------------- fused flash attention (32x32 MFMA, register-resident P) -----
// grid 1024 flat (XCD-clustered bh), 2 waves/block, 64 q/block (wave owns 32).
// Q pre-scaled so P = 2^S. K rows staged swap23-permuted; S^T C-layout -> exp2
// -> direct PV A-operand (register renaming only). 1 barrier/iter. LDS 32 KB.
__global__ __launch_bounds__(128, 2) void attn(
    const _Float16* __restrict__ Q, const _Float16* __restrict__ K,
    const _Float16* __restrict__ Vt, _Float16* __restrict__ ctx)
{
  const int tid = threadIdx.x;
  const int l   = tid & 63, wv = tid >> 6;
  const int lo5 = l & 31, hf = l >> 5;
  // XCD-aware mapping: all 32 q-blocks of a (b,h) on one XCD's L2
  const int id  = blockIdx.x;
  const int xcd = id & 7, j = id >> 3;
  const int bh  = xcd * 4 + (j >> 5);
  const int q0  = (j & 31) * 64;
  const int b   = bh >> 4, hd = bh & 15;
  __shared__ _Float16 sK[2][64 * 64];   // [slot-row][d], swizzled, rows swap23-permuted
  __shared__ _Float16 sV[2][64 * 64];   // [d][key], swizzled, natural

  // persistent Q B-frags: qf[kc] = Q[q = q0+wv*32+lo5][d = 16*kc + 8*hf .. +8]
  f16x8 qf[4];
  {
    const _Float16* Qg = Q + ((size_t)(b * S_LEN + q0 + wv * 32 + lo5)) * DM + hd * DKH + 8 * hf;
#pragma unroll
    for (int kc = 0; kc < 4; ++kc) qf[kc] = *(const f16x8*)(Qg + 16 * kc);
  }

  f32x16 o[2] = {};
  float l_part = 0.f;
  const f16x2 ones = {(_Float16)1.0f, (_Float16)1.0f};

  const _Float16* Kg0 = K + ((size_t)b * S_LEN) * DM + hd * DKH;
  const _Float16* Vg0 = Vt + ((size_t)bh * DKH) * S_LEN;

  // staging: 512 16B slots per array; thread handles slots tid + p*128.
  // slot s: LDS block s (linear); row r=s>>3; global block (s&7)^(r&7).
  // K global row = swap23(r); V rows are d (natural). Pointers loop-carried.
  const _Float16* gK[4]; const _Float16* gV[4];
  int ls[4];
#pragma unroll
  for (int p = 0; p < 4; ++p) {
    int s = tid + p * 128, r = s >> 3, g = (s & 7) ^ (r & 7);
    gK[p] = Kg0 + (size_t)swap23(r) * DM + g * 8;
    gV[p] = Vg0 + (size_t)r * S_LEN + g * 8;
    ls[p] = s * 8;
  }
  const int rx = lo5 & 7;   // frag-read block xor (row & 7)

  // prefetch tile 0 -> buffer 0
#pragma unroll
  for (int p = 0; p < 4; ++p) {
    gld16(gK[p], sK[0] + ls[p]);
    gld16(gV[p], sV[0] + ls[p]);
  }
  __syncthreads();

  for (int kt = 0; kt < S_LEN / 64; ++kt) {
    const int cur = kt & 1;
    if (kt < S_LEN / 64 - 1) {       // uniform branch; pointers advance by consts
#pragma unroll
      for (int p = 0; p < 4; ++p) {
        gK[p] += 64 * DM;
        gV[p] += 64;
        gld16(gK[p], sK[cur ^ 1] + ls[p]);
        gld16(gV[p], sV[cur ^ 1] + ls[p]);
      }
    }

    // S^T: C[slot-row][q] for 2 key-32-blocks; A=kf, B=qf (regs)
    f32x16 sAcc[2] = {};
#pragma unroll
    for (int kb = 0; kb < 2; ++kb)
#pragma unroll
      for (int kc = 0; kc < 4; ++kc) {
        f16x8 kf = *(const f16x8*)&sK[cur][(32 * kb + lo5) * 64 + ((2 * kc + hf) ^ rx) * 8];
        sAcc[kb] = __builtin_amdgcn_mfma_f32_32x32x16_f16(kf, qf[kc], sAcc[kb], 0, 0, 0);
      }

    // P = 2^S packed in C-reg order; pPv[kb][half] IS the PV A-operand for
    // chunk kc2 = 2*kb + half (swap23 aligns the layouts).
    f16x8 pPv[2][2];
#pragma unroll
    for (int kb = 0; kb < 2; ++kb)
#pragma unroll
      for (int half = 0; half < 2; ++half)
#pragma unroll
        for (int j2 = 0; j2 < 4; ++j2) {
          float p0 = fast_exp2(sAcc[kb][8 * half + 2 * j2]);
          float p1 = fast_exp2(sAcc[kb][8 * half + 2 * j2 + 1]);
          f16x2 pk = pk_f16(p0, p1);
          pPv[kb][half][2 * j2]     = pk[0];
          pPv[kb][half][2 * j2 + 1] = pk[1];
          l_part = __builtin_amdgcn_fdot2(__builtin_bit_cast(h16x2, pk),
                                          __builtin_bit_cast(h16x2, ones), l_part, false);
        }

    // PV: O[q][d] for 2 d-32-blocks; A = pPv (regs), B = vf from sV
#pragma unroll
    for (int db = 0; db < 2; ++db)
#pragma unroll
      for (int kc2 = 0; kc2 < 4; ++kc2) {
        f16x8 vf = *(const f16x8*)&sV[cur][(32 * db + lo5) * 64 + ((2 * kc2 + hf) ^ rx) * 8];
        o[db] = __builtin_amdgcn_mfma_f32_32x32x16_f16(pPv[kc2 >> 1][kc2 & 1], vf, o[db], 0, 0, 0);
      }

    __syncthreads();   // drains prefetch (vmcnt) + both waves done reading cur
  }

  // row sums: lane (lo5, hf) holds partial for q-row lo5; combine halves
  l_part += __shfl_xor(l_part, 32);
  float* lsum = (float*)&sK[0][0] + wv * 32;   // dead LDS; per-wave region
  if (hf == 0) lsum[lo5] = l_part;             // DS in-order within wave
  float inv[16];
#pragma unroll
  for (int r = 0; r < 16; ++r) {
    int qq = 8 * (r >> 2) + 4 * hf + (r & 3);
    inv[r] = 1.0f / lsum[qq];                  // broadcast reads
  }

  // store: o[db] C-layout: q = 8*(r>>2)+4*hf+(r&3), d = 32*db + lo5
  _Float16* Og = ctx + ((size_t)(b * S_LEN + q0 + wv * 32)) * DM + hd * DKH;
#pragma unroll
  for (int db = 0; db < 2; ++db)
#pragma unroll
    for (int r = 0; r < 16; ++r) {
      int qq = 8 * (r >> 2) + 4 * hf + (r & 3);
      Og[(size_t)qq * DM + 32 * db + lo5] = (_Float16)(o[db][r] * inv[r]);
    }
}

extern "C" void kernel_launch(void* const* d_in, const int* in_sizes, int n_in,
                              void* d_out, int out_size, void* d_ws, size_t ws_size,
                              hipStream_t stream)
{
  (void)in_sizes; (void)n_in; (void)out_size; (void)ws_size;
  const float* q  = (const float*)d_in[0];
  const float* k  = (const float*)d_in[1];
  const float* v  = (const float*)d_in[2];
  const float* wq = (const float*)d_in[3];
  const float* bq = (const float*)d_in[4];
  const float* wk = (const float*)d_in[5];
  const float* bk = (const float*)d_in[6];
  const float* wv = (const float*)d_in[7];
  const float* bv = (const float*)d_in[8];
  const float* wo = (const float*)d_in[9];
  const float* bo = (const float*)d_in[10];

  char* ws = (char*)d_ws;
  _Float16* XQ  = (_Float16*)(ws);                    // dead after proj3 -> CTX
  _Float16* XK  = (_Float16*)(ws + (8u  << 20));
  _Float16* XV  = (_Float16*)(ws + (16u << 20));
  _Float16* W16 = (_Float16*)(ws + (24u << 20));      // Wq,Wk,Wv,Wo
  _Float16* Qp  = (_Float16*)(ws + (32u << 20));
  _Float16* Kp  = (_Float16*)(ws + (40u << 20));
  _Float16* VT  = (_Float16*)(ws + (48u << 20));      // proj3 writes transposed V here
  _Float16* CTX = XQ;
  float* out = (float*)d_out;

  cvt_all<<<dim3(4096, 7), 256, 0, stream>>>(q, k, v, wq, wk, wv, wo, XQ, XK, XV, W16);
  proj3<<<dim3(8, 32, 3), 256, 0, stream>>>(XQ, XK, XV, W16, bq, bk, bv, Qp, Kp, VT);
  attn<<<dim3(1024), 128, 0, stream>>>(Qp, Kp, VT, CTX);
  out_gemm<<<dim3(8, 32), 256, 0, stream>>>(CTX, W16 + (size_t)3 * DM * DM, bo, out);
}